// Round 1
// baseline (394.815 us; speedup 1.0000x reference)
//
#include <hip/hip_runtime.h>
#include <hip/hip_bf16.h>

#define D_MODEL 1024
#define NH 16
#define HD 64
#define BATCH 2
#define SEQ 2048
#define M_TOTAL (BATCH*SEQ)   // 4096

typedef _Float16 f16;
typedef _Float16 half8 __attribute__((ext_vector_type(8)));
typedef _Float16 half4v __attribute__((ext_vector_type(4)));
typedef float floatx4 __attribute__((ext_vector_type(4)));

// ---------------- fp32 -> fp16 cast (vectorized) ----------------
__global__ void cvt_f32_f16(const float* __restrict__ src, f16* __restrict__ dst, int n4) {
    int i = blockIdx.x * blockDim.x + threadIdx.x;
    if (i < n4) {
        const float4* s = (const float4*)src;
        float4 v = s[i];
        half4v o = { (f16)v.x, (f16)v.y, (f16)v.z, (f16)v.w };
        *(half4v*)(dst + (long)i * 4) = o;
    }
}

// ---------------- fp32 [R][C] -> fp16 [C][R] transpose-cast ----------------
__global__ void transpose_cvt(const float* __restrict__ src, f16* __restrict__ dst, int R, int C) {
    __shared__ float tile[32][33];
    int tx = threadIdx.x;   // 0..31
    int ty = threadIdx.y;   // 0..7
    int c0 = blockIdx.x * 32;
    int r0 = blockIdx.y * 32;
    for (int yy = 0; yy < 32; yy += 8)
        tile[ty + yy][tx] = src[(long)(r0 + ty + yy) * C + c0 + tx];
    __syncthreads();
    for (int yy = 0; yy < 32; yy += 8)
        dst[(long)(c0 + ty + yy) * R + r0 + tx] = (f16)tile[tx][ty + yy];
}

// ---------------- 64x64-tile fp16 MFMA GEMM ----------------
// A: [M][Kdim] fp16 row-major; BT: [N][Kdim] fp16 (B transposed); bias fp32 [N]
// MODE 0: scatter epilogue into Q (scaled 1/8), K, V  as [B,H,S,64] fp16
// MODE 1: out[m][n] = acc + bias (fp32)
template<int MODE>
__global__ __launch_bounds__(256) void gemm16(
    const f16* __restrict__ A, const f16* __restrict__ BT,
    const float* __restrict__ bias,
    f16* __restrict__ Qh, f16* __restrict__ Kh, f16* __restrict__ Vh,
    float* __restrict__ out, int Kdim)
{
    __shared__ f16 Ah[64][40];   // pad 8: stride 80B, b128-aligned, conflict-light
    __shared__ f16 Bh[64][40];
    int tid  = threadIdx.x;
    int wid  = tid >> 6;
    int lane = tid & 63;
    int m0 = blockIdx.y * 64;
    int n0 = blockIdx.x * 64;
    int lrow = tid >> 2;          // 0..63
    int lkg  = (tid & 3) * 8;     // 0,8,16,24
    int l16  = lane & 15;
    int kgrp = (lane >> 4) * 8;

    floatx4 acc[4];
    #pragma unroll
    for (int nb = 0; nb < 4; nb++) acc[nb] = (floatx4){0.f, 0.f, 0.f, 0.f};

    for (int k0 = 0; k0 < Kdim; k0 += 32) {
        *(half8*)&Ah[lrow][lkg] = *(const half8*)&A[(long)(m0 + lrow) * Kdim + k0 + lkg];
        *(half8*)&Bh[lrow][lkg] = *(const half8*)&BT[(long)(n0 + lrow) * Kdim + k0 + lkg];
        __syncthreads();
        half8 af = *(const half8*)&Ah[wid * 16 + l16][kgrp];
        #pragma unroll
        for (int nb = 0; nb < 4; nb++) {
            half8 bf = *(const half8*)&Bh[nb * 16 + l16][kgrp];
            acc[nb] = __builtin_amdgcn_mfma_f32_16x16x32_f16(af, bf, acc[nb], 0, 0, 0);
        }
        __syncthreads();
    }

    #pragma unroll
    for (int nb = 0; nb < 4; nb++) {
        int n = n0 + nb * 16 + l16;
        float bv = bias[n];
        #pragma unroll
        for (int r = 0; r < 4; r++) {
            int m = m0 + wid * 16 + (lane >> 4) * 4 + r;   // D row = quad*4+reg
            float v = acc[nb][r] + bv;
            if (MODE == 0) {
                int head = n / 192;
                int rem  = n % 192;
                int t    = rem / 64;
                int d    = rem % 64;
                int b    = m >> 11;       // /2048
                int s    = m & 2047;
                long idx = ((long)(b * NH + head) * SEQ + s) * HD + d;
                if (t == 0)      Qh[idx] = (f16)(v * 0.125f);  // fold 1/sqrt(64)
                else if (t == 1) Kh[idx] = (f16)v;
                else             Vh[idx] = (f16)v;
            } else {
                out[(long)m * D_MODEL + n] = v;
            }
        }
    }
}

// ---------------- flash-style attention ----------------
// grid: (S/64, B*H), block 256 (4 waves); each wave owns 16 query rows.
__global__ __launch_bounds__(256) void attn(
    const f16* __restrict__ Qh, const f16* __restrict__ Kh, const f16* __restrict__ Vh,
    const float* __restrict__ mask, f16* __restrict__ valh)
{
    __shared__ f16 Kl[32][72];       // [key][d], pad to 72
    __shared__ f16 Vt[64][40];       // [d][key] (transposed at stage), pad to 40
    __shared__ f16 Pl[4][16][40];    // per-wave P: [q][key]
    int tid  = threadIdx.x;
    int wid  = tid >> 6;
    int lane = tid & 63;
    int bh = blockIdx.y;
    int b  = bh >> 4;
    int h  = bh & 15;
    int q0 = blockIdx.x * 64 + wid * 16;
    int quad = lane >> 4;
    int l16  = lane & 15;

    const f16* Qbase = Qh + ((long)bh * SEQ + q0) * HD;
    half8 qf0 = *(const half8*)&Qbase[(long)l16 * HD + quad * 8];
    half8 qf1 = *(const half8*)&Qbase[(long)l16 * HD + 32 + quad * 8];

    float m_i[4], l_i[4];
    floatx4 Of[4];
    #pragma unroll
    for (int r = 0; r < 4; r++) { m_i[r] = -3e38f; l_i[r] = 0.f; }
    #pragma unroll
    for (int nb = 0; nb < 4; nb++) Of[nb] = (floatx4){0.f, 0.f, 0.f, 0.f};

    int srow = tid >> 3;          // 0..31 (key row)
    int sdg  = (tid & 7) * 8;     // d group
    const f16* Kb = Kh + (long)bh * SEQ * HD;
    const f16* Vb = Vh + (long)bh * SEQ * HD;

    for (int k0 = 0; k0 < SEQ; k0 += 32) {
        __syncthreads();
        *(half8*)&Kl[srow][sdg] = *(const half8*)&Kb[(long)(k0 + srow) * HD + sdg];
        half8 vtmp = *(const half8*)&Vb[(long)(k0 + srow) * HD + sdg];
        #pragma unroll
        for (int j = 0; j < 8; j++) Vt[sdg + j][srow] = vtmp[j];
        __syncthreads();

        floatx4 sc[2];
        #pragma unroll
        for (int blk = 0; blk < 2; blk++) {
            half8 kf0 = *(const half8*)&Kl[blk * 16 + l16][quad * 8];
            half8 kf1 = *(const half8*)&Kl[blk * 16 + l16][32 + quad * 8];
            floatx4 s = (floatx4){0.f, 0.f, 0.f, 0.f};
            s = __builtin_amdgcn_mfma_f32_16x16x32_f16(qf0, kf0, s, 0, 0, 0);
            s = __builtin_amdgcn_mfma_f32_16x16x32_f16(qf1, kf1, s, 0, 0, 0);
            int colg = k0 + blk * 16 + l16;
            #pragma unroll
            for (int r = 0; r < 4; r++) {
                int rowg = q0 + quad * 4 + r;
                s[r] += mask[(long)rowg * SEQ + colg];
            }
            sc[blk] = s;
        }

        float newm[4], alpha[4];
        #pragma unroll
        for (int r = 0; r < 4; r++) {
            float t = fmaxf(sc[0][r], sc[1][r]);
            t = fmaxf(t, __shfl_xor(t, 1));
            t = fmaxf(t, __shfl_xor(t, 2));
            t = fmaxf(t, __shfl_xor(t, 4));
            t = fmaxf(t, __shfl_xor(t, 8));
            newm[r]  = fmaxf(m_i[r], t);
            alpha[r] = __expf(m_i[r] - newm[r]);
            m_i[r]   = newm[r];
        }

        float p[2][4];
        #pragma unroll
        for (int r = 0; r < 4; r++) {
            float ps = 0.f;
            #pragma unroll
            for (int blk = 0; blk < 2; blk++) {
                float pv = __expf(sc[blk][r] - newm[r]);
                p[blk][r] = pv;
                ps += pv;
            }
            ps += __shfl_xor(ps, 1);
            ps += __shfl_xor(ps, 2);
            ps += __shfl_xor(ps, 4);
            ps += __shfl_xor(ps, 8);
            l_i[r] = l_i[r] * alpha[r] + ps;
        }

        #pragma unroll
        for (int blk = 0; blk < 2; blk++)
            #pragma unroll
            for (int r = 0; r < 4; r++)
                Pl[wid][quad * 4 + r][blk * 16 + l16] = (f16)p[blk][r];

        #pragma unroll
        for (int nb = 0; nb < 4; nb++)
            #pragma unroll
            for (int r = 0; r < 4; r++) Of[nb][r] *= alpha[r];

        // wave-private LDS write->read: compiler inserts lgkmcnt wait, no barrier needed
        half8 pf = *(const half8*)&Pl[wid][l16][quad * 8];
        #pragma unroll
        for (int nb = 0; nb < 4; nb++) {
            half8 vf = *(const half8*)&Vt[nb * 16 + l16][quad * 8];
            Of[nb] = __builtin_amdgcn_mfma_f32_16x16x32_f16(pf, vf, Of[nb], 0, 0, 0);
        }
    }

    #pragma unroll
    for (int nb = 0; nb < 4; nb++) {
        #pragma unroll
        for (int r = 0; r < 4; r++) {
            int q = q0 + quad * 4 + r;
            int d = nb * 16 + l16;
            float v = Of[nb][r] / l_i[r];
            valh[((long)(b * SEQ + q)) * D_MODEL + h * HD + d] = (f16)v;
        }
    }
}

extern "C" void kernel_launch(void* const* d_in, const int* in_sizes, int n_in,
                              void* d_out, int out_size, void* d_ws, size_t ws_size,
                              hipStream_t stream) {
    const float* x    = (const float*)d_in[0];
    const float* mask = (const float*)d_in[1];
    const float* Wqkv = (const float*)d_in[2];
    const float* bqkv = (const float*)d_in[3];
    const float* Wout = (const float*)d_in[4];
    const float* bout = (const float*)d_in[5];
    float* out = (float*)d_out;

    char* ws = (char*)d_ws;
    f16* xh    = (f16*)(ws + 0);          //  8 MB: [4096][1024]
    f16* WqkvT = (f16*)(ws + 8388608);    //  6 MB: [3072][1024]
    f16* WoutT = (f16*)(ws + 14680064);   //  2 MB: [1024][1024]
    f16* Qh    = (f16*)(ws + 16777216);   //  8 MB: [32][2048][64] (pre-scaled 1/8)
    f16* Kh    = (f16*)(ws + 25165824);   //  8 MB
    f16* Vh    = (f16*)(ws + 33554432);   //  8 MB
    f16* valh  = (f16*)(ws + 41943040);   //  8 MB: [4096][1024]

    cvt_f32_f16<<<4096, 256, 0, stream>>>(x, xh, M_TOTAL * D_MODEL / 4);
    transpose_cvt<<<dim3(96, 32), dim3(32, 8), 0, stream>>>(Wqkv, WqkvT, 1024, 3072);
    transpose_cvt<<<dim3(32, 32), dim3(32, 8), 0, stream>>>(Wout, WoutT, 1024, 1024);
    gemm16<0><<<dim3(48, 64), 256, 0, stream>>>(xh, WqkvT, bqkv, Qh, Kh, Vh, nullptr, 1024);
    attn<<<dim3(32, 32), 256, 0, stream>>>(Qh, Kh, Vh, mask, valh);
    gemm16<1><<<dim3(16, 64), 256, 0, stream>>>(valh, WoutT, bout, nullptr, nullptr, nullptr, out, 1024);
}

// Round 2
// 246.646 us; speedup vs baseline: 1.6007x; 1.6007x over previous
//
#include <hip/hip_runtime.h>
#include <hip/hip_bf16.h>

#define D_MODEL 1024
#define NH 16
#define HD 64
#define BATCH 2
#define SEQ 2048
#define M_TOTAL (BATCH*SEQ)   // 4096

typedef _Float16 f16;
typedef _Float16 half8 __attribute__((ext_vector_type(8)));
typedef _Float16 half4v __attribute__((ext_vector_type(4)));
typedef float floatx4 __attribute__((ext_vector_type(4)));

__device__ inline void gload_lds16(const void* g, void* l) {
    __builtin_amdgcn_global_load_lds(
        (const __attribute__((address_space(1))) unsigned int*)g,
        (__attribute__((address_space(3))) unsigned int*)l, 16, 0, 0);
}

// ---------------- fp32 -> fp16 cast (vectorized) ----------------
__global__ void cvt_f32_f16(const float* __restrict__ src, f16* __restrict__ dst, int n4) {
    int i = blockIdx.x * blockDim.x + threadIdx.x;
    if (i < n4) {
        const float4* s = (const float4*)src;
        float4 v = s[i];
        half4v o = { (f16)v.x, (f16)v.y, (f16)v.z, (f16)v.w };
        *(half4v*)(dst + (long)i * 4) = o;
    }
}

// ---------------- fp32 [R][C] -> fp16 [C][R] transpose-cast ----------------
__global__ void transpose_cvt(const float* __restrict__ src, f16* __restrict__ dst, int R, int C) {
    __shared__ float tile[32][33];
    int tx = threadIdx.x;
    int ty = threadIdx.y;
    int c0 = blockIdx.x * 32;
    int r0 = blockIdx.y * 32;
    for (int yy = 0; yy < 32; yy += 8)
        tile[ty + yy][tx] = src[(long)(r0 + ty + yy) * C + c0 + tx];
    __syncthreads();
    for (int yy = 0; yy < 32; yy += 8)
        dst[(long)(c0 + ty + yy) * R + r0 + tx] = (f16)tile[tx][ty + yy];
}

// ---------------- row-max of mask ----------------
__global__ void mask_rowmax(const float* __restrict__ mask, float* __restrict__ mm) {
    int row = blockIdx.x;
    const float* r = mask + (long)row * SEQ;
    float m = -3e38f;
    for (int i = threadIdx.x; i < SEQ; i += 256) m = fmaxf(m, r[i]);
    for (int off = 1; off < 64; off <<= 1) m = fmaxf(m, __shfl_xor(m, off));
    __shared__ float red[4];
    if ((threadIdx.x & 63) == 0) red[threadIdx.x >> 6] = m;
    __syncthreads();
    if (threadIdx.x == 0)
        mm[row] = fmaxf(fmaxf(red[0], red[1]), fmaxf(red[2], red[3]));
}

// ---------------- 128x128-tile fp16 MFMA GEMM (m97 structure) ----------------
// A: [M][Kdim] fp16 row-major; BT: [N][Kdim] fp16; bias fp32 [N]
// MODE 0: scatter epilogue -> Qh [bh][s][d] (x0.125), Kh [bh][s][d], Vtg [bh][d][s]
// MODE 1: out[m][n] = acc + bias (fp32)
template<int MODE>
__global__ __launch_bounds__(256) void gemm128(
    const f16* __restrict__ A, const f16* __restrict__ BT,
    const float* __restrict__ bias,
    f16* __restrict__ Qh, f16* __restrict__ Kh, f16* __restrict__ Vtg,
    float* __restrict__ out, int Kdim)
{
    __shared__ f16 Ah[128 * 32];   // unpadded: required by global_load_lds
    __shared__ f16 Bh[128 * 32];
    int tid  = threadIdx.x;
    int wid  = tid >> 6;
    int lane = tid & 63;
    int quad = lane >> 4;
    int l16  = lane & 15;
    int m0 = blockIdx.y * 128;
    int n0 = blockIdx.x * 128;
    int srow = lane >> 2;         // 0..15
    int scol = (lane & 3) * 8;    // f16 col within 32
    int mrow = (wid >> 1) * 64;
    int ncol = (wid & 1) * 64;

    floatx4 acc[4][4];
    #pragma unroll
    for (int mb = 0; mb < 4; mb++)
        #pragma unroll
        for (int nb = 0; nb < 4; nb++) acc[mb][nb] = (floatx4){0.f, 0.f, 0.f, 0.f};

    const f16* Abase = A + (long)m0 * Kdim;
    const f16* Bbase = BT + (long)n0 * Kdim;

    for (int k0 = 0; k0 < Kdim; k0 += 32) {
        #pragma unroll
        for (int j = 0; j < 2; j++) {
            int rbase = (wid * 2 + j) * 16;
            gload_lds16(Abase + (long)(rbase + srow) * Kdim + k0 + scol, &Ah[rbase * 32]);
            gload_lds16(Bbase + (long)(rbase + srow) * Kdim + k0 + scol, &Bh[rbase * 32]);
        }
        __syncthreads();
        half8 af[4];
        #pragma unroll
        for (int mb = 0; mb < 4; mb++)
            af[mb] = *(const half8*)&Ah[(mrow + mb * 16 + l16) * 32 + quad * 8];
        #pragma unroll
        for (int nb = 0; nb < 4; nb++) {
            half8 bf = *(const half8*)&Bh[(ncol + nb * 16 + l16) * 32 + quad * 8];
            #pragma unroll
            for (int mb = 0; mb < 4; mb++)
                acc[mb][nb] = __builtin_amdgcn_mfma_f32_16x16x32_f16(af[mb], bf, acc[mb][nb], 0, 0, 0);
        }
        __syncthreads();
    }

    #pragma unroll
    for (int nb = 0; nb < 4; nb++) {
        int n = n0 + ncol + nb * 16 + l16;
        float bv = bias[n];
        int head = 0, t = 0, d = 0;
        if (MODE == 0) { head = n / 192; int rem = n % 192; t = rem / 64; d = rem % 64; }
        #pragma unroll
        for (int mb = 0; mb < 4; mb++) {
            int mbase = m0 + mrow + mb * 16 + quad * 4;
            if (MODE == 0) {
                int b = mbase >> 11;
                int s = mbase & 2047;
                long bh = b * NH + head;
                if (t == 2) {
                    half4v pack;
                    #pragma unroll
                    for (int r = 0; r < 4; r++) pack[r] = (f16)(acc[mb][nb][r] + bv);
                    *(half4v*)&Vtg[(bh * HD + d) * SEQ + s] = pack;
                } else if (t == 0) {
                    #pragma unroll
                    for (int r = 0; r < 4; r++)
                        Qh[(bh * SEQ + s + r) * HD + d] = (f16)((acc[mb][nb][r] + bv) * 0.125f);
                } else {
                    #pragma unroll
                    for (int r = 0; r < 4; r++)
                        Kh[(bh * SEQ + s + r) * HD + d] = (f16)(acc[mb][nb][r] + bv);
                }
            } else {
                #pragma unroll
                for (int r = 0; r < 4; r++)
                    out[(long)(mbase + r) * D_MODEL + n] = acc[mb][nb][r] + bv;
            }
        }
    }
}

// ---------------- flash-style attention, shuffle-free softmax ----------------
// grid: (S/64, B*H), block 256 (4 waves); each wave owns 16 query rows; KB=64.
__global__ __launch_bounds__(256, 4) void attn(
    const f16* __restrict__ Qh, const f16* __restrict__ Kh, const f16* __restrict__ Vtg,
    const float* __restrict__ mask, const float* __restrict__ mm, f16* __restrict__ valh)
{
    __shared__ f16 Kl[64 * 72];      // [key][d], stride 72 f16 (even bank spread)
    __shared__ f16 Vt[64 * 72];      // [d][key]
    __shared__ f16 Pl[4][16 * 68];   // per-wave P: [q][key], stride 68
    int tid  = threadIdx.x;
    int wid  = tid >> 6;
    int lane = tid & 63;
    int quad = lane >> 4;
    int l16  = lane & 15;
    int bh = blockIdx.y;
    int b  = bh >> 4;
    int h  = bh & 15;
    int q0 = blockIdx.x * 64 + wid * 16;

    const f16* Qbase = Qh + ((long)bh * SEQ + q0) * HD;
    half8 qf0 = *(const half8*)&Qbase[(long)l16 * HD + quad * 8];
    half8 qf1 = *(const half8*)&Qbase[(long)l16 * HD + 32 + quad * 8];

    float mml[4];
    #pragma unroll
    for (int r = 0; r < 4; r++) mml[r] = mm[q0 + quad * 4 + r];

    floatx4 Of[4];
    float sums[4] = {0.f, 0.f, 0.f, 0.f};
    #pragma unroll
    for (int nb = 0; nb < 4; nb++) Of[nb] = (floatx4){0.f, 0.f, 0.f, 0.f};

    int srow = tid >> 2;          // 0..63
    int scg  = (tid & 3) * 16;
    const f16* Kb = Kh + (long)bh * SEQ * HD;
    const f16* Vb = Vtg + (long)bh * HD * SEQ;

    for (int k0 = 0; k0 < SEQ; k0 += 64) {
        __syncthreads();
        *(half8*)&Kl[srow * 72 + scg]     = *(const half8*)&Kb[(long)(k0 + srow) * HD + scg];
        *(half8*)&Kl[srow * 72 + scg + 8] = *(const half8*)&Kb[(long)(k0 + srow) * HD + scg + 8];
        *(half8*)&Vt[srow * 72 + scg]     = *(const half8*)&Vb[(long)srow * SEQ + k0 + scg];
        *(half8*)&Vt[srow * 72 + scg + 8] = *(const half8*)&Vb[(long)srow * SEQ + k0 + scg + 8];
        __syncthreads();

        floatx4 sc[4];
        #pragma unroll
        for (int kb = 0; kb < 4; kb++) {
            half8 kf0 = *(const half8*)&Kl[(kb * 16 + l16) * 72 + quad * 8];
            half8 kf1 = *(const half8*)&Kl[(kb * 16 + l16) * 72 + 32 + quad * 8];
            floatx4 s = (floatx4){0.f, 0.f, 0.f, 0.f};
            s = __builtin_amdgcn_mfma_f32_16x16x32_f16(qf0, kf0, s, 0, 0, 0);
            s = __builtin_amdgcn_mfma_f32_16x16x32_f16(qf1, kf1, s, 0, 0, 0);
            sc[kb] = s;
        }

        #pragma unroll
        for (int kb = 0; kb < 4; kb++) {
            int colg = k0 + kb * 16 + l16;
            #pragma unroll
            for (int r = 0; r < 4; r++) {
                float sv = sc[kb][r] + mask[(long)(q0 + quad * 4 + r) * SEQ + colg];
                float p = __expf(sv - mml[r]);
                sums[r] += p;
                Pl[wid][(quad * 4 + r) * 68 + kb * 16 + l16] = (f16)p;
            }
        }

        // wave-private LDS round-trip (C-layout -> A-layout); no barrier needed
        half8 pf0 = *(const half8*)&Pl[wid][l16 * 68 + quad * 8];
        half8 pf1 = *(const half8*)&Pl[wid][l16 * 68 + 32 + quad * 8];
        #pragma unroll
        for (int nb = 0; nb < 4; nb++) {
            half8 vf0 = *(const half8*)&Vt[(nb * 16 + l16) * 72 + quad * 8];
            half8 vf1 = *(const half8*)&Vt[(nb * 16 + l16) * 72 + 32 + quad * 8];
            Of[nb] = __builtin_amdgcn_mfma_f32_16x16x32_f16(pf0, vf0, Of[nb], 0, 0, 0);
            Of[nb] = __builtin_amdgcn_mfma_f32_16x16x32_f16(pf1, vf1, Of[nb], 0, 0, 0);
        }
    }

    #pragma unroll
    for (int r = 0; r < 4; r++) {
        float s = sums[r];
        s += __shfl_xor(s, 1);
        s += __shfl_xor(s, 2);
        s += __shfl_xor(s, 4);
        s += __shfl_xor(s, 8);
        sums[r] = 1.f / s;
    }

    #pragma unroll
    for (int nb = 0; nb < 4; nb++) {
        #pragma unroll
        for (int r = 0; r < 4; r++) {
            int q = q0 + quad * 4 + r;
            int d = nb * 16 + l16;
            valh[((long)(b * SEQ + q)) * D_MODEL + h * HD + d] = (f16)(Of[nb][r] * sums[r]);
        }
    }
}

extern "C" void kernel_launch(void* const* d_in, const int* in_sizes, int n_in,
                              void* d_out, int out_size, void* d_ws, size_t ws_size,
                              hipStream_t stream) {
    const float* x    = (const float*)d_in[0];
    const float* mask = (const float*)d_in[1];
    const float* Wqkv = (const float*)d_in[2];
    const float* bqkv = (const float*)d_in[3];
    const float* Wout = (const float*)d_in[4];
    const float* bout = (const float*)d_in[5];
    float* out = (float*)d_out;

    char* ws = (char*)d_ws;
    f16* xh    = (f16*)(ws + 0);          //  8 MB: [4096][1024]
    f16* WqkvT = (f16*)(ws + 8388608);    //  6 MB: [3072][1024]
    f16* WoutT = (f16*)(ws + 14680064);   //  2 MB: [1024][1024]
    f16* Qh    = (f16*)(ws + 16777216);   //  8 MB: [32][2048][64] (pre-scaled 1/8)
    f16* Kh    = (f16*)(ws + 25165824);   //  8 MB: [32][2048][64]
    f16* Vtg   = (f16*)(ws + 33554432);   //  8 MB: [32][64][2048]  (V transposed)
    f16* valh  = (f16*)(ws + 41943040);   //  8 MB: [4096][1024]
    float* mmax = (float*)(ws + 50331648); // 8 KB: [2048]

    cvt_f32_f16<<<4096, 256, 0, stream>>>(x, xh, M_TOTAL * D_MODEL / 4);
    transpose_cvt<<<dim3(96, 32), dim3(32, 8), 0, stream>>>(Wqkv, WqkvT, 1024, 3072);
    transpose_cvt<<<dim3(32, 32), dim3(32, 8), 0, stream>>>(Wout, WoutT, 1024, 1024);
    mask_rowmax<<<2048, 256, 0, stream>>>(mask, mmax);
    gemm128<0><<<dim3(24, 32), 256, 0, stream>>>(xh, WqkvT, bqkv, Qh, Kh, Vtg, nullptr, 1024);
    attn<<<dim3(32, 32), 256, 0, stream>>>(Qh, Kh, Vtg, mask, mmax, valh);
    gemm128<1><<<dim3(8, 32), 256, 0, stream>>>(valh, WoutT, bout, nullptr, nullptr, nullptr, out, 1024);
}

// Round 3
// 229.733 us; speedup vs baseline: 1.7186x; 1.0736x over previous
//
#include <hip/hip_runtime.h>
#include <hip/hip_bf16.h>

#define D_MODEL 1024
#define NH 16
#define HD 64
#define BATCH 2
#define SEQ 2048
#define M_TOTAL (BATCH*SEQ)   // 4096

typedef _Float16 f16;
typedef _Float16 half8 __attribute__((ext_vector_type(8)));
typedef _Float16 half4v __attribute__((ext_vector_type(4)));
typedef float floatx4 __attribute__((ext_vector_type(4)));

__device__ inline void gload_lds16(const void* g, void* l) {
    __builtin_amdgcn_global_load_lds(
        (const __attribute__((address_space(1))) unsigned int*)g,
        (__attribute__((address_space(3))) unsigned int*)l, 16, 0, 0);
}

// ---------------- fp32 -> fp16 cast ----------------
__global__ void cvt_f32_f16(const float* __restrict__ src, f16* __restrict__ dst, int n4) {
    int i = blockIdx.x * blockDim.x + threadIdx.x;
    if (i < n4) {
        float4 v = ((const float4*)src)[i];
        half4v o = { (f16)v.x, (f16)v.y, (f16)v.z, (f16)v.w };
        *(half4v*)(dst + (long)i * 4) = o;
    }
}

// ---------------- E = exp(mask) in f16 ----------------
__global__ void exp_cvt(const float* __restrict__ src, f16* __restrict__ dst, int n4) {
    int i = blockIdx.x * blockDim.x + threadIdx.x;
    if (i < n4) {
        float4 v = ((const float4*)src)[i];
        half4v o = { (f16)__expf(v.x), (f16)__expf(v.y), (f16)__expf(v.z), (f16)__expf(v.w) };
        *(half4v*)(dst + (long)i * 4) = o;
    }
}

// ---------------- fp32 [R][C] -> fp16 [C][R] transpose-cast ----------------
__global__ void transpose_cvt(const float* __restrict__ src, f16* __restrict__ dst, int R, int C) {
    __shared__ float tile[32][33];
    int tx = threadIdx.x;
    int ty = threadIdx.y;
    int c0 = blockIdx.x * 32;
    int r0 = blockIdx.y * 32;
    for (int yy = 0; yy < 32; yy += 8)
        tile[ty + yy][tx] = src[(long)(r0 + ty + yy) * C + c0 + tx];
    __syncthreads();
    for (int yy = 0; yy < 32; yy += 8)
        dst[(long)(c0 + ty + yy) * R + r0 + tx] = (f16)tile[tx][ty + yy];
}

// ---------------- 128xTN-tile fp16 MFMA GEMM, BK=64, XOR-swizzled LDS ----------------
// A: [M][Kdim] f16; BT: [N][Kdim] f16; bias fp32 [N]
// LDS rows stride 64 f16 (unpadded, required by global_load_lds); 16B chunk at
// position p within row r holds global chunk (p ^ (r&7)) -> conflict-free b128 frag reads.
// MODE 0 (TN=128): scatter -> Qh [bh][s][d] (x0.125), Kh [bh][s][d], Vtg [bh][d][s]
// MODE 1 (TN=64):  out[m][n] = acc + bias (fp32)
template<int MODE, int TN>
__global__ __launch_bounds__(256) void gemm_mfma(
    const f16* __restrict__ A, const f16* __restrict__ BT,
    const float* __restrict__ bias,
    f16* __restrict__ Qh, f16* __restrict__ Kh, f16* __restrict__ Vtg,
    float* __restrict__ out, int Kdim)
{
    constexpr int NF = TN / 32;          // n-frags per wave
    __shared__ f16 Ah[128 * 64];
    __shared__ f16 Bh[TN * 64];
    int tid  = threadIdx.x;
    int wid  = tid >> 6;
    int lane = tid & 63;
    int quad = lane >> 4;
    int l16  = lane & 15;
    int m0 = blockIdx.y * 128;
    int n0 = blockIdx.x * TN;
    int mrow = (wid >> 1) * 64;
    int ncol = (wid & 1) * (TN / 2);
    // staging: lane -> row (lane>>3) within 8-row group, global chunk (lane&7)^(row&7)
    int grow = lane >> 3;                 // 0..7
    int gchunk = (lane & 7) ^ (grow & 7); // swizzled source chunk
    // frag-read swizzled chunk offsets (f16 units), lane-constant
    int sw0 = ((quad)     ^ (l16 & 7)) * 8;   // k-half 0
    int sw1 = ((quad + 4) ^ (l16 & 7)) * 8;   // k-half 1

    floatx4 acc[4][NF];
    #pragma unroll
    for (int mb = 0; mb < 4; mb++)
        #pragma unroll
        for (int nb = 0; nb < NF; nb++) acc[mb][nb] = (floatx4){0.f, 0.f, 0.f, 0.f};

    const f16* Abase = A + (long)m0 * Kdim;
    const f16* Bbase = BT + (long)n0 * Kdim;

    for (int k0 = 0; k0 < Kdim; k0 += 64) {
        #pragma unroll
        for (int j = 0; j < 4; j++) {
            int r = j * 32 + wid * 8 + grow;
            gload_lds16(Abase + (long)r * Kdim + k0 + gchunk * 8, &Ah[(j * 32 + wid * 8) * 64]);
        }
        #pragma unroll
        for (int j = 0; j < TN / 32; j++) {
            int r = j * 32 + wid * 8 + grow;
            gload_lds16(Bbase + (long)r * Kdim + k0 + gchunk * 8, &Bh[(j * 32 + wid * 8) * 64]);
        }
        __syncthreads();
        #pragma unroll
        for (int h = 0; h < 2; h++) {
            int sw = h ? sw1 : sw0;
            half8 af[4];
            #pragma unroll
            for (int mb = 0; mb < 4; mb++)
                af[mb] = *(const half8*)&Ah[(mrow + mb * 16 + l16) * 64 + sw];
            #pragma unroll
            for (int nb = 0; nb < NF; nb++) {
                half8 bf = *(const half8*)&Bh[(ncol + nb * 16 + l16) * 64 + sw];
                #pragma unroll
                for (int mb = 0; mb < 4; mb++)
                    acc[mb][nb] = __builtin_amdgcn_mfma_f32_16x16x32_f16(af[mb], bf, acc[mb][nb], 0, 0, 0);
            }
        }
        __syncthreads();
    }

    #pragma unroll
    for (int nb = 0; nb < NF; nb++) {
        int n = n0 + ncol + nb * 16 + l16;
        float bv = bias[n];
        int head = 0, t = 0, d = 0;
        if (MODE == 0) { head = n / 192; int rem = n % 192; t = rem / 64; d = rem % 64; }
        #pragma unroll
        for (int mb = 0; mb < 4; mb++) {
            int mbase = m0 + mrow + mb * 16 + quad * 4;
            if (MODE == 0) {
                int b = mbase >> 11;
                int s = mbase & 2047;
                long bh = b * NH + head;
                if (t == 2) {
                    half4v pack;
                    #pragma unroll
                    for (int r = 0; r < 4; r++) pack[r] = (f16)(acc[mb][nb][r] + bv);
                    *(half4v*)&Vtg[(bh * HD + d) * SEQ + s] = pack;
                } else if (t == 0) {
                    #pragma unroll
                    for (int r = 0; r < 4; r++)
                        Qh[(bh * SEQ + s + r) * HD + d] = (f16)((acc[mb][nb][r] + bv) * 0.125f);
                } else {
                    #pragma unroll
                    for (int r = 0; r < 4; r++)
                        Kh[(bh * SEQ + s + r) * HD + d] = (f16)(acc[mb][nb][r] + bv);
                }
            } else {
                #pragma unroll
                for (int r = 0; r < 4; r++)
                    out[(long)(mbase + r) * D_MODEL + n] = acc[mb][nb][r] + bv;
            }
        }
    }
}

// ---------------- flash attention: 32 q-rows/wave, swizzled DMA staging ----------------
// grid (SEQ/128, B*H), 256 threads; p = E[q][key] * exp(qk/8), softmax denom deferred.
__global__ __launch_bounds__(256) void attn(
    const f16* __restrict__ Qh, const f16* __restrict__ Kh, const f16* __restrict__ Vtg,
    const f16* __restrict__ E, f16* __restrict__ valh)
{
    __shared__ f16 Kl[64 * 64];      // [key][d], swizzled chunks
    __shared__ f16 Vt[64 * 64];      // [d][key], swizzled chunks
    __shared__ f16 Pl[4][32 * 68];   // per-wave P [q][key], stride 68 (write-conflict-free)
    int tid  = threadIdx.x;
    int wid  = tid >> 6;
    int lane = tid & 63;
    int quad = lane >> 4;
    int l16  = lane & 15;
    int bh = blockIdx.y;
    int b  = bh >> 4;
    int h  = bh & 15;
    int q0 = blockIdx.x * 128 + wid * 32;

    int grow = lane >> 3;
    int gchunk = (lane & 7) ^ (grow & 7);
    int sw0 = ((quad)     ^ (l16 & 7)) * 8;
    int sw1 = ((quad + 4) ^ (l16 & 7)) * 8;

    const f16* Qbase = Qh + ((long)bh * SEQ + q0) * HD;
    half8 qf[2][2];
    #pragma unroll
    for (int m = 0; m < 2; m++)
        #pragma unroll
        for (int c = 0; c < 2; c++)
            qf[m][c] = *(const half8*)&Qbase[(long)(m * 16 + l16) * HD + c * 32 + quad * 8];

    floatx4 Of[2][4];
    float sums[2][4];
    #pragma unroll
    for (int m = 0; m < 2; m++) {
        #pragma unroll
        for (int nb = 0; nb < 4; nb++) Of[m][nb] = (floatx4){0.f, 0.f, 0.f, 0.f};
        #pragma unroll
        for (int r = 0; r < 4; r++) sums[m][r] = 0.f;
    }

    const f16* Kb = Kh + (long)bh * SEQ * HD;
    const f16* Vb = Vtg + (long)bh * HD * SEQ;

    for (int k0 = 0; k0 < SEQ; k0 += 64) {
        __syncthreads();
        #pragma unroll
        for (int j = 0; j < 2; j++) {
            int r = j * 32 + wid * 8 + grow;
            gload_lds16(Kb + (long)(k0 + r) * HD + gchunk * 8, &Kl[(j * 32 + wid * 8) * 64]);
            gload_lds16(Vb + (long)r * SEQ + k0 + gchunk * 8, &Vt[(j * 32 + wid * 8) * 64]);
        }
        __syncthreads();

        // prefetch E tile values (overlaps with QK MFMAs)
        f16 ef[2][4][4];
        #pragma unroll
        for (int m = 0; m < 2; m++)
            #pragma unroll
            for (int r = 0; r < 4; r++) {
                const f16* Erow = E + (long)(q0 + m * 16 + quad * 4 + r) * SEQ + k0 + l16;
                #pragma unroll
                for (int kb = 0; kb < 4; kb++) ef[m][r][kb] = Erow[kb * 16];
            }

        floatx4 sc[2][4];
        #pragma unroll
        for (int kb = 0; kb < 4; kb++) {
            half8 kf0 = *(const half8*)&Kl[(kb * 16 + l16) * 64 + sw0];
            half8 kf1 = *(const half8*)&Kl[(kb * 16 + l16) * 64 + sw1];
            #pragma unroll
            for (int m = 0; m < 2; m++) {
                floatx4 s = (floatx4){0.f, 0.f, 0.f, 0.f};
                s = __builtin_amdgcn_mfma_f32_16x16x32_f16(qf[m][0], kf0, s, 0, 0, 0);
                s = __builtin_amdgcn_mfma_f32_16x16x32_f16(qf[m][1], kf1, s, 0, 0, 0);
                sc[m][kb] = s;
            }
        }

        #pragma unroll
        for (int m = 0; m < 2; m++)
            #pragma unroll
            for (int kb = 0; kb < 4; kb++)
                #pragma unroll
                for (int r = 0; r < 4; r++) {
                    float p = (float)ef[m][r][kb] * __expf(sc[m][kb][r]);
                    sums[m][r] += p;
                    Pl[wid][(m * 16 + quad * 4 + r) * 68 + kb * 16 + l16] = (f16)p;
                }

        // wave-private LDS round-trip (C-layout -> A-layout); no barrier needed
        half8 pf[2][2];
        #pragma unroll
        for (int m = 0; m < 2; m++)
            #pragma unroll
            for (int c = 0; c < 2; c++)
                pf[m][c] = *(const half8*)&Pl[wid][(m * 16 + l16) * 68 + c * 32 + quad * 8];

        #pragma unroll
        for (int nb = 0; nb < 4; nb++) {
            half8 vf0 = *(const half8*)&Vt[(nb * 16 + l16) * 64 + sw0];
            half8 vf1 = *(const half8*)&Vt[(nb * 16 + l16) * 64 + sw1];
            #pragma unroll
            for (int m = 0; m < 2; m++) {
                Of[m][nb] = __builtin_amdgcn_mfma_f32_16x16x32_f16(pf[m][0], vf0, Of[m][nb], 0, 0, 0);
                Of[m][nb] = __builtin_amdgcn_mfma_f32_16x16x32_f16(pf[m][1], vf1, Of[m][nb], 0, 0, 0);
            }
        }
    }

    #pragma unroll
    for (int m = 0; m < 2; m++)
        #pragma unroll
        for (int r = 0; r < 4; r++) {
            float s = sums[m][r];
            s += __shfl_xor(s, 1);
            s += __shfl_xor(s, 2);
            s += __shfl_xor(s, 4);
            s += __shfl_xor(s, 8);
            sums[m][r] = 1.f / s;
        }

    #pragma unroll
    for (int m = 0; m < 2; m++)
        #pragma unroll
        for (int nb = 0; nb < 4; nb++)
            #pragma unroll
            for (int r = 0; r < 4; r++) {
                int q = q0 + m * 16 + quad * 4 + r;
                int d = nb * 16 + l16;
                valh[((long)(b * SEQ + q)) * D_MODEL + h * HD + d] = (f16)(Of[m][nb][r] * sums[m][r]);
            }
}

extern "C" void kernel_launch(void* const* d_in, const int* in_sizes, int n_in,
                              void* d_out, int out_size, void* d_ws, size_t ws_size,
                              hipStream_t stream) {
    const float* x    = (const float*)d_in[0];
    const float* mask = (const float*)d_in[1];
    const float* Wqkv = (const float*)d_in[2];
    const float* bqkv = (const float*)d_in[3];
    const float* Wout = (const float*)d_in[4];
    const float* bout = (const float*)d_in[5];
    float* out = (float*)d_out;

    char* ws = (char*)d_ws;
    f16* xh    = (f16*)(ws + 0);          // 8 MB: [4096][1024]; dead after gemm0
    f16* E     = (f16*)(ws + 0);          // 8 MB: [2048][2048] exp(mask) — overlays xh
    f16* WqkvT = (f16*)(ws + 8388608);    // 6 MB: [3072][1024]
    f16* WoutT = (f16*)(ws + 14680064);   // 2 MB: [1024][1024]
    f16* Qh    = (f16*)(ws + 16777216);   // 8 MB: [32][2048][64] (pre-scaled 1/8)
    f16* Kh    = (f16*)(ws + 25165824);   // 8 MB: [32][2048][64]
    f16* Vtg   = (f16*)(ws + 33554432);   // 8 MB: [32][64][2048] (V transposed)
    f16* valh  = (f16*)(ws + 41943040);   // 8 MB: [4096][1024]

    cvt_f32_f16<<<4096, 256, 0, stream>>>(x, xh, M_TOTAL * D_MODEL / 4);
    transpose_cvt<<<dim3(96, 32), dim3(32, 8), 0, stream>>>(Wqkv, WqkvT, 1024, 3072);
    transpose_cvt<<<dim3(32, 32), dim3(32, 8), 0, stream>>>(Wout, WoutT, 1024, 1024);
    gemm_mfma<0, 128><<<dim3(24, 32), 256, 0, stream>>>(xh, WqkvT, bqkv, Qh, Kh, Vtg, nullptr, 1024);
    exp_cvt<<<4096, 256, 0, stream>>>(mask, E, SEQ * SEQ / 4);   // xh dead now
    attn<<<dim3(16, 32), 256, 0, stream>>>(Qh, Kh, Vtg, E, valh);
    gemm_mfma<1, 64><<<dim3(16, 32), 256, 0, stream>>>(valh, WoutT, bout, nullptr, nullptr, nullptr, out, 1024);
}